// Round 7
// baseline (22806.921 us; speedup 1.0000x reference)
//
#include <hip/hip_runtime.h>
#include <hip/hip_cooperative_groups.h>

// Problem constants (fixed by setup_inputs / reference)
constexpr int   NROWS   = 131072;
constexpr int   KCOLS   = 512;
constexpr int   KP1     = 513;   // + dummy column
constexpr float PA      = 1.0f / 131072.0f;
constexpr float PB_REAL = 0.5f / 512.0f;
constexpr float PB_DUM  = 0.5f;
constexpr float FI      = (float)(1.0 / 1.1); // GAMMA/(GAMMA+EPSILON)
constexpr float STOPERR = 1e-6f;
constexpr int   MAXIT   = 1000;
constexpr float LOG2E   = 1.4426950408889634f;
constexpr float CQ      = 10.0f * LOG2E;      // (1/EPSILON)*log2(e)
constexpr float LN2     = 0.6931471805599453f;

// Cooperative config (PROVEN in round 5): 256 blocks x 1024 threads,
// launch_bounds(1024,4). Custom grid barrier, no cg::sync, no L2 flushes.
constexpr int BLOCKS  = 256;
constexpr int THREADS = 1024;
constexpr int WPB     = THREADS / 64;     // 16 waves per block
constexpr int NWAVES  = BLOCKS * WPB;     // 4096 waves
// NROWS / NWAVES = 32 rows per wave, in 4 groups of 8 (unroll)

// Workspace layout (floats). Total ~1.01 MB (proven ws_size >= 1.58 MB).
constexpr size_t OFF_LSE = 0;                        // [NROWS] row logsumexp
constexpr size_t OFF_A   = (size_t)NROWS;            // [NROWS] scaling a
constexpr int    KPAD    = 520;
constexpr size_t OFF_B0  = 2 * (size_t)NROWS;        // [KPAD] b ping     (sc-only)
constexpr size_t OFF_B1  = OFF_B0 + KPAD;            // [KPAD] b pong     (sc-only)
constexpr size_t OFF_BF  = OFF_B0 + 2 * KPAD;        // [KPAD] b final    (normal)
constexpr size_t OFF_D0  = OFF_B0 + 3 * KPAD;        // [KPAD] delta ping (sc-only)
constexpr size_t OFF_D1  = OFF_B0 + 4 * KPAD;        // [KPAD] delta pong (sc-only)

// Big scratch lives in the d_out tail (d_out = 256 MiB):
//   [0, 128 MiB)   qhi  ushort[NROWS*KCOLS]
//   [128, 192 MiB) qlo  uchar[NROWS*KCOLS]
//   [192 MiB, ...) colp float[KP1*BLOCKS] transposed (0.5 MB)
//   [200 MiB, ...) barrier words (cnt, gen)
// plan_epilogue overwrites all of d_out at the end (loop finished by then).
constexpr size_t QLO_BYTE_OFF  = (size_t)NROWS * KCOLS * 2;   // 128 MiB
constexpr size_t COLP_BYTE_OFF = 192ull * 1024 * 1024;
constexpr size_t BAR_BYTE_OFF  = 200ull * 1024 * 1024;

__device__ __forceinline__ float waveReduceSum(float v) {
#pragma unroll
  for (int s = 32; s >= 1; s >>= 1) v += __shfl_xor(v, s);
  return v;
}
__device__ __forceinline__ float waveReduceMax(float v) {
#pragma unroll
  for (int s = 32; s >= 1; s >>= 1) v = fmaxf(v, __shfl_xor(v, s));
  return v;
}

// device-coherent (agent-scope) accessors: bypass non-coherent L2, hit LLC.
__device__ __forceinline__ float scload(const float* p) {
  return __hip_atomic_load(p, __ATOMIC_RELAXED, __HIP_MEMORY_SCOPE_AGENT);
}
__device__ __forceinline__ void scstore(float* p, float v) {
  __hip_atomic_store(p, v, __ATOMIC_RELAXED, __HIP_MEMORY_SCOPE_AGENT);
}

// reconstruct 8 f32 Q values (24-bit: hi ushort + lo byte) from packed loads
__device__ __forceinline__ void unpack8(const uint4 h, const uint2 l, float q[8]) {
  q[0] = __uint_as_float((h.x << 16)         | ((l.x << 8) & 0xff00u));
  q[1] = __uint_as_float((h.x & 0xffff0000u) | ( l.x       & 0xff00u));
  q[2] = __uint_as_float((h.y << 16)         | ((l.x >> 8) & 0xff00u));
  q[3] = __uint_as_float((h.y & 0xffff0000u) | ((l.x >> 16)& 0xff00u));
  q[4] = __uint_as_float((h.z << 16)         | ((l.y << 8) & 0xff00u));
  q[5] = __uint_as_float((h.z & 0xffff0000u) | ( l.y       & 0xff00u));
  q[6] = __uint_as_float((h.w << 16)         | ((l.y >> 8) & 0xff00u));
  q[7] = __uint_as_float((h.w & 0xffff0000u) | ((l.y >> 16)& 0xff00u));
}

// ---------------------------------------------------------------------------
// Kernel 1: per-row logsumexp + 24-bit Q planes (into d_out) + state init.
// ---------------------------------------------------------------------------
__global__ __launch_bounds__(1024) void lse_q_init_kernel(
    const float* __restrict__ logits, float* __restrict__ ws,
    unsigned short* __restrict__ qhi, unsigned char* __restrict__ qlo,
    unsigned* __restrict__ bar) {
  float* lse = ws + OFF_LSE;
  const int nw   = (gridDim.x * blockDim.x) >> 6;
  const int gw   = (blockIdx.x * blockDim.x + threadIdx.x) >> 6;
  const int lane = threadIdx.x & 63;

  for (int r = gw; r < NROWS; r += nw) {
    const float4* row4 = reinterpret_cast<const float4*>(logits + (size_t)r * KCOLS);
    float4 x0 = row4[lane];
    float4 x1 = row4[64 + lane];
    float m = fmaxf(fmaxf(fmaxf(x0.x, x0.y), fmaxf(x0.z, x0.w)),
                    fmaxf(fmaxf(x1.x, x1.y), fmaxf(x1.z, x1.w)));
    m = waveReduceMax(m);
    float s = exp2f((x0.x - m) * LOG2E) + exp2f((x0.y - m) * LOG2E)
            + exp2f((x0.z - m) * LOG2E) + exp2f((x0.w - m) * LOG2E)
            + exp2f((x1.x - m) * LOG2E) + exp2f((x1.y - m) * LOG2E)
            + exp2f((x1.z - m) * LOG2E) + exp2f((x1.w - m) * LOG2E);
    s = waveReduceSum(s);
    float L = m + log2f(s) * LN2;
    if (lane == 0) lse[r] = L;
    unsigned u[8];
    u[0] = __float_as_uint(exp2f((x0.x - L) * CQ)) + 0x80u;
    u[1] = __float_as_uint(exp2f((x0.y - L) * CQ)) + 0x80u;
    u[2] = __float_as_uint(exp2f((x0.z - L) * CQ)) + 0x80u;
    u[3] = __float_as_uint(exp2f((x0.w - L) * CQ)) + 0x80u;
    u[4] = __float_as_uint(exp2f((x1.x - L) * CQ)) + 0x80u;
    u[5] = __float_as_uint(exp2f((x1.y - L) * CQ)) + 0x80u;
    u[6] = __float_as_uint(exp2f((x1.z - L) * CQ)) + 0x80u;
    u[7] = __float_as_uint(exp2f((x1.w - L) * CQ)) + 0x80u;
    ushort4 hA, hB;  uchar4 lA, lB;
    hA.x = (unsigned short)(u[0] >> 16); lA.x = (unsigned char)(u[0] >> 8);
    hA.y = (unsigned short)(u[1] >> 16); lA.y = (unsigned char)(u[1] >> 8);
    hA.z = (unsigned short)(u[2] >> 16); lA.z = (unsigned char)(u[2] >> 8);
    hA.w = (unsigned short)(u[3] >> 16); lA.w = (unsigned char)(u[3] >> 8);
    hB.x = (unsigned short)(u[4] >> 16); lB.x = (unsigned char)(u[4] >> 8);
    hB.y = (unsigned short)(u[5] >> 16); lB.y = (unsigned char)(u[5] >> 8);
    hB.z = (unsigned short)(u[6] >> 16); lB.z = (unsigned char)(u[6] >> 8);
    hB.w = (unsigned short)(u[7] >> 16); lB.w = (unsigned char)(u[7] >> 8);
    *reinterpret_cast<ushort4*>(qhi + (size_t)r * KCOLS + 4 * lane)       = hA;
    *reinterpret_cast<ushort4*>(qhi + (size_t)r * KCOLS + 256 + 4 * lane) = hB;
    *reinterpret_cast<uchar4*>(qlo + (size_t)r * KCOLS + 4 * lane)        = lA;
    *reinterpret_cast<uchar4*>(qlo + (size_t)r * KCOLS + 256 + 4 * lane)  = lB;
  }
  if (blockIdx.x == 0 && threadIdx.x < KP1)
    ws[OFF_B0 + threadIdx.x] = 1.0f / 513.0f;
  if (blockIdx.x == 0 && threadIdx.x == 0) {
    bar[0]  = 0u;   // arrival counter (cumulative)
    bar[32] = 0u;   // generation
  }
}

// ---------------------------------------------------------------------------
// Kernel 2 (cooperative, custom barrier): Sinkhorn while-loop on LLC-resident
// 24-bit Q, 8-row unroll, Aitken extrapolation every 8 iterations.
// All cross-block data moves through agent-scope atomics (no L2 flushes).
// ---------------------------------------------------------------------------
__global__ __launch_bounds__(THREADS, 4) void sinkhorn_loop(
    const unsigned short* __restrict__ qhi, const unsigned char* __restrict__ qlo,
    float* __restrict__ ws, float* __restrict__ colp, unsigned* __restrict__ bar) {
  float* a    = ws + OFF_A;
  float* b0   = ws + OFF_B0;
  float* b1   = ws + OFF_B1;
  float* bfin = ws + OFF_BF;
  float* dl0  = ws + OFF_D0;
  float* dl1  = ws + OFF_D1;
  unsigned* cnt = bar;
  unsigned* gen = bar + 32;

  __shared__ float lds[WPB][KPAD];   // 16*520*4 = 33,280 B
  __shared__ float s_err, s_s1, s_s2;
  __shared__ int   s_nbar;
  __shared__ int   s_dead;

  const int tid  = threadIdx.x;
  const int wv   = tid >> 6;
  const int lane = tid & 63;
  const int bk   = blockIdx.x;
  const int gw   = bk * WPB + wv;   // global wave id [0, 4096)

  if (tid == 0) { s_nbar = 0; s_dead = 0; }
  __syncthreads();

  // Grid barrier: __syncthreads drains vmcnt before s_barrier, so retired
  // agent-scope stores are LLC-visible before arrival. (Proven round 5.)
  auto gridBar = [&]() {
    __syncthreads();
    if (tid == 0) {
      int nb = s_nbar;
      unsigned old = atomicAdd(cnt, 1u);
      if (old == (unsigned)(nb * BLOCKS + (BLOCKS - 1))) {
        atomicAdd(gen, 1u);
      } else if (!s_dead) {
        int spins = 0;
        while (__hip_atomic_load(gen, __ATOMIC_RELAXED, __HIP_MEMORY_SCOPE_AGENT)
               <= (unsigned)nb) {
          __builtin_amdgcn_s_sleep(1);
          if (++spins > (1 << 24)) { s_dead = 1; break; }  // fail-fast
        }
      }
      s_nbar = nb + 1;
    }
    __syncthreads();
  };

  float err = 1.0f;
  int it = 0;
  for (; it < MAXIT; ++it) {
    if (!(err > STOPERR)) break;   // NaN err also stops (matches JAX)

    const float* bcv = (it & 1) ? b1 : b0;
    float*       bnv = (it & 1) ? b0 : b1;
    float*       dcu = (it & 1) ? dl1 : dl0;   // this iter's delta
    const float* dpr = (it & 1) ? dl0 : dl1;   // previous iter's delta

    // stage current b (written remotely last iter -> agent-scope loads)
    float rb[8];
#pragma unroll
    for (int e = 0; e < 8; ++e) rb[e] = scload(&bcv[8 * lane + e]);
    float bdum = scload(&bcv[512]);

    // ---- phase A: rows, 8-row unroll (16 outstanding loads per wave) ----
    float cp[8] = {0.f, 0.f, 0.f, 0.f, 0.f, 0.f, 0.f, 0.f};
    float adum = 0.f;
    for (int r = gw; r < NROWS; r += 8 * NWAVES) {
      uint4 h[8];  uint2 l[8];
#pragma unroll
      for (int u = 0; u < 8; ++u) {
        const int rr = r + u * NWAVES;
        h[u] = ((const uint4*)(qhi + (size_t)rr * KCOLS))[lane];
        l[u] = ((const uint2*)(qlo + (size_t)rr * KCOLS))[lane];
      }
      float d[8];
#pragma unroll
      for (int u = 0; u < 8; ++u) {
        float q[8];
        unpack8(h[u], l[u], q);
        float dd = 0.f;
#pragma unroll
        for (int e = 0; e < 8; ++e) dd = fmaf(q[e], rb[e], dd);
        d[u] = dd;
      }
#pragma unroll
      for (int s = 32; s >= 1; s >>= 1) {   // 8 interleaved butterflies
#pragma unroll
        for (int u = 0; u < 8; ++u) d[u] += __shfl_xor(d[u], s);
      }
      float ai[8];
#pragma unroll
      for (int u = 0; u < 8; ++u) ai[u] = PA / (d[u] + bdum);
      if (lane == 0) {
#pragma unroll
        for (int u = 0; u < 8; ++u) a[r + u * NWAVES] = ai[u];
      }
#pragma unroll
      for (int u = 0; u < 8; ++u) {
        float q[8];
        unpack8(h[u], l[u], q);   // recompute to keep live-register count low
#pragma unroll
        for (int e = 0; e < 8; ++e) cp[e] = fmaf(ai[u], q[e], cp[e]);
        adum += ai[u];
      }
    }
    // combine 16 waves' partials in LDS -> transposed colp (agent-scope)
#pragma unroll
    for (int e = 0; e < 8; ++e) lds[wv][8 * lane + e] = cp[e];
    if (lane == 0) lds[wv][512] = adum;
    __syncthreads();
    for (int t = tid; t < KP1; t += THREADS) {
      float s = 0.f;
#pragma unroll
      for (int w2 = 0; w2 < WPB; ++w2) s += lds[w2][t];
      scstore(&colp[(size_t)t * BLOCKS + bk], s);
    }
    gridBar();

    // ---- phase B: 2 cols per block (+ dummy col on block 0, wave 2) ----
    {
      int jcol = (wv == 0) ? 2 * bk
               : (wv == 1) ? 2 * bk + 1
               : (bk == 0 && wv == 2) ? 512 : -1;
      if (jcol >= 0) {
        float s = 0.f;
#pragma unroll
        for (int e = 0; e < 4; ++e)
          s += scload(&colp[(size_t)jcol * BLOCKS + 4 * lane + e]);
        s = waveReduceSum(s);
        if (lane == 0) {
          float bj = (jcol < KCOLS) ? powf(PB_REAL / s, FI) : (PB_DUM / s);
          scstore(&bnv[jcol], bj);
          scstore(&dcu[jcol], bj - scload(&bcv[jcol]));
        }
      }
    }
    gridBar();

    // ---- err + rho: identical fixed-order reduction in every block ----
    if (wv == 0) {
      float s0 = 0.f, s1 = 0.f, s2 = 0.f;
      for (int t = lane; t < KP1; t += 64) {
        float dc = scload(&dcu[t]);
        float dp = scload(&dpr[t]);
        s0 += dc * dc;  s1 += dc * dp;  s2 += dp * dp;
      }
#pragma unroll
      for (int s = 32; s >= 1; s >>= 1) {
        s0 += __shfl_xor(s0, s);
        s1 += __shfl_xor(s1, s);
        s2 += __shfl_xor(s2, s);
      }
      if (lane == 0) { s_err = sqrtf(s0); s_s1 = s1; s_s2 = s2; }
    }
    __syncthreads();
    err = s_err;

    // ---- Aitken extrapolation every 8 iters (uniform decision grid-wide:
    //      err/s1/s2 are bit-identical in every block by construction) ----
    if ((it & 7) == 7 && err > 10.0f * STOPERR) {
      float rho = (s_s2 > 0.f) ? (s_s1 / s_s2) : 0.f;
      if (rho > 0.5f && rho < 0.95f) {
        float c = rho / (1.0f - rho);
        int jcol = (wv == 0) ? 2 * bk
                 : (wv == 1) ? 2 * bk + 1
                 : (bk == 0 && wv == 2) ? 512 : -1;
        if (jcol >= 0 && lane == 0) {
          float bx = scload(&bnv[jcol]) + c * scload(&dcu[jcol]);
          if (bx > 1e-30f) scstore(&bnv[jcol], bx);  // positivity guard
        }
        gridBar();   // taken by ALL blocks (condition is uniform)
      }
    }
  }

  // publish final b for the epilogue (bodies executed = it)
  if (bk == 0) {
    const float* bf = (it & 1) ? b1 : b0;
    for (int t = tid; t < KP1; t += THREADS) bfin[t] = scload(&bf[t]);
  }
}

// ---------------------------------------------------------------------------
// Kernel 3: plan = n * a * Q * b^T, recomputing Q in f32 from logits+lse
// (d_out, which held Q planes + loop scratch, is overwritten with the plan).
// ---------------------------------------------------------------------------
__global__ __launch_bounds__(1024) void plan_epilogue(
    const float* __restrict__ logits, const float* __restrict__ ws,
    float* __restrict__ out) {
  const float* lse  = ws + OFF_LSE;
  const float* a    = ws + OFF_A;
  const float* bfin = ws + OFF_BF;
  const int nw   = (gridDim.x * blockDim.x) >> 6;
  const int gw   = (blockIdx.x * blockDim.x + threadIdx.x) >> 6;
  const int lane = threadIdx.x & 63;

  const float4* b4 = reinterpret_cast<const float4*>(bfin);
  float4 rb0 = b4[lane];        // b[4l..4l+3]
  float4 rb1 = b4[64 + lane];   // b[256+4l..256+4l+3]

  for (int r = gw; r < NROWS; r += nw) {
    const float4* row4 = reinterpret_cast<const float4*>(logits + (size_t)r * KCOLS);
    float4*       out4 = reinterpret_cast<float4*>(out + (size_t)r * KCOLS);
    float L  = lse[r];
    float na = a[r] * (float)NROWS;   // n * a_i
    float4 x0 = row4[lane];
    float4 x1 = row4[64 + lane];
    float4 o0, o1;
    o0.x = na * exp2f((x0.x - L) * CQ) * rb0.x;
    o0.y = na * exp2f((x0.y - L) * CQ) * rb0.y;
    o0.z = na * exp2f((x0.z - L) * CQ) * rb0.z;
    o0.w = na * exp2f((x0.w - L) * CQ) * rb0.w;
    o1.x = na * exp2f((x1.x - L) * CQ) * rb1.x;
    o1.y = na * exp2f((x1.y - L) * CQ) * rb1.y;
    o1.z = na * exp2f((x1.z - L) * CQ) * rb1.z;
    o1.w = na * exp2f((x1.w - L) * CQ) * rb1.w;
    out4[lane]      = o0;
    out4[64 + lane] = o1;
  }
}

extern "C" void kernel_launch(void* const* d_in, const int* in_sizes, int n_in,
                              void* d_out, int out_size, void* d_ws, size_t ws_size,
                              hipStream_t stream) {
  (void)in_sizes; (void)n_in; (void)out_size; (void)ws_size;
  const float*    logits = (const float*)d_in[0];
  float*          out    = (float*)d_out;
  float*          ws     = (float*)d_ws;    // needs ~1.01 MB (proven safe)
  unsigned short* qhi    = (unsigned short*)d_out;                          // 128 MiB
  unsigned char*  qlo    = (unsigned char*)d_out + QLO_BYTE_OFF;            //  64 MiB
  float*          colp   = (float*)((char*)d_out + COLP_BYTE_OFF);          // 0.5 MiB
  unsigned*       bar    = (unsigned*)((char*)d_out + BAR_BYTE_OFF);        // 132 B

  hipLaunchKernelGGL(lse_q_init_kernel, dim3(1024), dim3(1024), 0, stream,
                     logits, ws, qhi, qlo, bar);

  const unsigned short* qhArg = qhi;
  const unsigned char*  qlArg = qlo;
  float*                wsArg = ws;
  float*                cpArg = colp;
  unsigned*             brArg = bar;
  void* args[] = { (void*)&qhArg, (void*)&qlArg, (void*)&wsArg,
                   (void*)&cpArg, (void*)&brArg };
  hipLaunchCooperativeKernel((void*)sinkhorn_loop, dim3(BLOCKS), dim3(THREADS),
                             args, 0, stream);

  hipLaunchKernelGGL(plan_epilogue, dim3(2048), dim3(1024), 0, stream,
                     logits, ws, out);
}